// Round 8
// baseline (84.194 us; speedup 1.0000x reference)
//
#include <hip/hip_runtime.h>

// ---- problem constants ----
constexpr int  Bn    = 512;
constexpr int  Dd    = 128;
constexpr int  QUEUE = 65536;
constexpr int  NEGR  = 8192;              // B*N in-batch negatives
constexpr int  NJ    = NEGR + QUEUE;      // 73728 negative columns
constexpr long long OUTC    = 1 + NJ;     // 73729 out row stride
constexpr long long MEM_OFF = 2LL * Bn * OUTC;  // new_memory offset in d_out

// fused-kernel block ranges
// gemm: 512 blocks x 144 cols -> EXACTLY 2 gemm blocks per CU (512 = 2*256),
// fixing the R3/R7 tail (32 CUs had 2x write work). Column split keeps B reads
// at 1x (R5's m-split re-read B 4x and lost). Inner store structure (LDS
// transpose + dwordx4 cooperative stores) unchanged from proven R7.
constexpr int GEMM_BLK = 512;
constexpr int CPB      = 144;             // cols per gemm block (9 groups of 16)
constexpr int POS_BLK  = Bn / 4;          // 128 blocks, 4 rows each (4 waves)
constexpr int MEM_BLK  = 256;             // one memory-copy block per CU
constexpr int TOT_BLK  = GEMM_BLK + POS_BLK + MEM_BLK;

constexpr int LDS_STRIDE = 148;           // 16x144 f32 tile, +4 pad: row pitch
                                          // 592B (16B-aligned), banks spread

typedef __attribute__((ext_vector_type(8))) short  short8;
typedef __attribute__((ext_vector_type(4))) float  floatx4;

__device__ __forceinline__ unsigned short f2bf(float f) {
    union { float f; unsigned u; } x; x.f = f;
    unsigned u = x.u;
    u += 0x7fffu + ((u >> 16) & 1u);   // round-to-nearest-even
    return (unsigned short)(u >> 16);
}

__device__ __forceinline__ short8 pack8(float4 a, float4 b) {
    short8 r;
    r[0] = (short)f2bf(a.x); r[1] = (short)f2bf(a.y);
    r[2] = (short)f2bf(a.z); r[3] = (short)f2bf(a.w);
    r[4] = (short)f2bf(b.x); r[5] = (short)f2bf(b.y);
    r[6] = (short)f2bf(b.z); r[7] = (short)f2bf(b.w);
    return r;
}

// ---- kernel 0: q (512x128 f32) -> bf16 in workspace ----
__global__ void qconv(const float* __restrict__ q, unsigned short* __restrict__ qb) {
    int t = blockIdx.x * blockDim.x + threadIdx.x;      // 16384 threads, 4 elems each
    float4 v = *(const float4*)(q + (long long)t * 4);
    ushort4 r;
    r.x = f2bf(v.x); r.y = f2bf(v.y); r.z = f2bf(v.z); r.w = f2bf(v.w);
    *(ushort4*)(qb + (long long)t * 4) = r;
}

// ---- fused kernel: [0,512) gemm | [512,640) positive col | [640,896) memory copy ----
__global__ __launch_bounds__(256) void fused(const unsigned short* __restrict__ qb,
                                             const float* __restrict__ negs,
                                             const float* __restrict__ mem,
                                             const float* __restrict__ q,
                                             const float* __restrict__ k,
                                             const float* __restrict__ ps,
                                             const float* __restrict__ k_all,
                                             const int* __restrict__ indexp,
                                             float* __restrict__ out) {
    __shared__ float tile[16 * LDS_STRIDE];   // 9.5 KB, only used by gemm blocks

    const int blk  = blockIdx.x;
    const int lane = threadIdx.x & 63;
    const int wave = threadIdx.x >> 6;

    if (blk < GEMM_BLK) {
        // ---- GEMM: 144 cols/block, 9 j-groups over 4 waves {3,2,2,2} ----
        const int l16 = lane & 15;
        const int kg  = lane >> 4;        // 0..3
        const int klo = kg * 8;
        // XCD swizzle: 512 = 8 * 64 -> adjacent stripes on same XCD's L2
        const int stripe = (blk & 7) * 64 + (blk >> 3);
        const long long jbase0 = (long long)stripe * CPB;          // block col base
        const int goff = (wave == 0) ? 0 : (2 * wave + 1);         // group offset
        const int ng   = (wave == 0) ? 3 : 2;                      // groups this wave

        // B fragments: up to 3 j-groups x 4 k-slices; statically indexed
        short8 bfrag[3][4];
        #pragma unroll
        for (int g = 0; g < 3; ++g) {
            if (g < ng) {
                const long long jrow = jbase0 + (goff + g) * 16 + l16;
                const float* src = (jrow < NEGR) ? (negs + jrow * Dd)
                                                 : (mem + (jrow - NEGR) * Dd);
                #pragma unroll
                for (int s = 0; s < 4; ++s) {
                    float4 x = *(const float4*)(src + s * 32 + klo);
                    float4 y = *(const float4*)(src + s * 32 + klo + 4);
                    bfrag[g][s] = pack8(x, y);
                }
            }
        }

        #pragma unroll 1
        for (int m = 0; m < 32; ++m) {
            const unsigned short* arow = qb + (long long)(m * 16 + l16) * Dd + klo;
            short8 af[4];
            #pragma unroll
            for (int s = 0; s < 4; ++s) af[s] = *(const short8*)(arow + s * 32);
            // compute, scale, stage into LDS (transpose: MFMA layout scatters a
            // wave over 4 rows -> misaligned segments; staged stores are wide)
            #pragma unroll
            for (int g = 0; g < 3; ++g) {
                if (g < ng) {
                    floatx4 acc = {0.f, 0.f, 0.f, 0.f};
                    #pragma unroll
                    for (int s = 0; s < 4; ++s)
                        acc = __builtin_amdgcn_mfma_f32_16x16x32_bf16(af[s], bfrag[g][s], acc, 0, 0, 0);
                    const int tcol = (goff + g) * 16 + l16;
                    #pragma unroll
                    for (int r = 0; r < 4; ++r)
                        tile[(kg * 4 + r) * LDS_STRIDE + tcol] = acc[r] * 10.0f;
                }
            }
            __syncthreads();
            // cooperative dwordx4 write-out: 16x144 floats = 576 float4 chunks,
            // flat-indexed over 256 threads (2 full passes + 64 threads).
            #pragma unroll
            for (int pass = 0; pass < 3; ++pass) {
                const int idx = pass * 256 + threadIdx.x;
                if (idx < 576) {
                    const int trow = idx / 36;       // 36 float4 per row
                    const int c    = idx % 36;
                    const float4 v = *(const float4*)&tile[trow * LDS_STRIDE + c * 4];
                    const long long grow = (long long)(m * 16 + trow);
                    float* dst = out + grow * OUTC + 1 + jbase0 + c * 4;
                    *(float4*)dst               = v;
                    *(float4*)(dst + Bn * OUTC) = v;
                }
            }
            __syncthreads();
        }
    } else if (blk < GEMM_BLK + POS_BLK) {
        // ---- positive logits -> out column 0 (one wave per batch row) ----
        const int b = (blk - GEMM_BLK) * 4 + wave;
        float2 qv = *(const float2*)(q + (long long)b * Dd + lane * 2);
        float2 kv = *(const float2*)(k + (long long)b * Dd + lane * 2);
        float pk = qv.x * kv.x + qv.y * kv.y;
        float pp = 0.f;
        #pragma unroll
        for (int p = 0; p < 4; ++p) {
            float2 pv = *(const float2*)(ps + ((long long)b * 4 + p) * Dd + lane * 2);
            pp += qv.x * pv.x + qv.y * pv.y;
        }
        #pragma unroll
        for (int off = 32; off; off >>= 1) {
            pk += __shfl_xor(pk, off);
            pp += __shfl_xor(pp, off);
        }
        if (lane == 0) {
            out[(long long)b * OUTC]        = pk * 10.0f;
            out[((long long)b + Bn) * OUTC] = (pp * 0.25f) * 10.0f;
        }
    } else {
        // ---- new_memory = memory with rows (i+index)%Q <- k_all[i] ----
        float* outmem = out + MEM_OFF;
        const int index = *indexp;
        const long long total = (long long)QUEUE * (Dd / 4);   // float4 chunks
        const long long stride = (long long)MEM_BLK * 256;
        for (long long i = (long long)(blk - GEMM_BLK - POS_BLK) * 256 + threadIdx.x;
             i < total; i += stride) {
            int row = (int)(i >> 5);          // D/4 = 32 chunks per row
            int c4  = (int)(i & 31);
            int src = (row - index) & (QUEUE - 1);
            float4 v;
            if (src < Bn) v = *(const float4*)(k_all + (long long)src * Dd + c4 * 4);
            else          v = *(const float4*)(mem   + (long long)row * Dd + c4 * 4);
            *(float4*)(outmem + (long long)row * Dd + c4 * 4) = v;
        }
    }
}

extern "C" void kernel_launch(void* const* d_in, const int* in_sizes, int n_in,
                              void* d_out, int out_size, void* d_ws, size_t ws_size,
                              hipStream_t stream) {
    const float* q      = (const float*)d_in[0];
    const float* k      = (const float*)d_in[1];
    const float* pos    = (const float*)d_in[2];
    const float* negs   = (const float*)d_in[3];
    const float* k_all  = (const float*)d_in[4];
    const float* memory = (const float*)d_in[5];
    const int*   indexp = (const int*)d_in[6];
    float* out = (float*)d_out;
    unsigned short* qb = (unsigned short*)d_ws;   // 512*128*2 = 128 KB

    qconv<<<64, 256, 0, stream>>>(q, qb);
    fused<<<TOT_BLK, 256, 0, stream>>>(qb, negs, memory, q, k, pos, k_all, indexp, out);
}